// Round 7
// baseline (409.957 us; speedup 1.0000x reference)
//
#include <hip/hip_runtime.h>

// ---------------- problem constants ----------------
#define Bb 8
#define Tt 1024
#define Hh 8
#define DKk 64
#define NFf 512
#define DCc 256

typedef _Float16 v2h __attribute__((ext_vector_type(2)));
typedef _Float16 v4h __attribute__((ext_vector_type(4)));
typedef _Float16 v8h __attribute__((ext_vector_type(8)));
typedef float    v4f __attribute__((ext_vector_type(4)));
typedef float    v16f __attribute__((ext_vector_type(16)));

#define MFMA16(a,b,c) __builtin_amdgcn_mfma_f32_16x16x16f16((a),(b),(c),0,0,0)
#define MFMA32(a,b,c) __builtin_amdgcn_mfma_f32_16x16x32_f16((a),(b),(c),0,0,0)
#define MFMA3216(a,b,c) __builtin_amdgcn_mfma_f32_32x32x16_f16((a),(b),(c),0,0,0)

// scale folded into q: 1/sqrt(64) * log2(e)  (scores live in log2 domain)
#define SCQ 0.1803368801111f

__device__ inline void st8(_Float16* dst, v8h x){
    *(v4h*)dst     = __builtin_shufflevector(x,x,0,1,2,3);
    *(v4h*)(dst+4) = __builtin_shufflevector(x,x,4,5,6,7);
}

__device__ inline v8h cvt8(float4 a, float4 b){
    v8h r;
    r[0]=(_Float16)a.x; r[1]=(_Float16)a.y; r[2]=(_Float16)a.z; r[3]=(_Float16)a.w;
    r[4]=(_Float16)b.x; r[5]=(_Float16)b.y; r[6]=(_Float16)b.z; r[7]=(_Float16)b.w;
    return r;
}

// XOR swizzle for [R][64] half LDS tiles; keeps 8-half granularity
__device__ inline int swz(int r, int c){ return (r*64 + c) ^ ((r&7)<<3); }

// ---------------- LayerNorm: x (8192,512) fp32 -> xn fp16 ----------------
__global__ __launch_bounds__(256) void k_ln(const float* __restrict__ x,
                                            const float* __restrict__ g,
                                            const float* __restrict__ be,
                                            _Float16* __restrict__ xn){
    int row = blockIdx.x; int tid = threadIdx.x;
    const float* xr = x + (size_t)row*512;
    float2 v = reinterpret_cast<const float2*>(xr)[tid];
    float s = v.x + v.y, sq = v.x*v.x + v.y*v.y;
    for (int off=32; off; off>>=1){ s += __shfl_down(s, off); sq += __shfl_down(sq, off); }
    __shared__ float ws_[4], wq_[4];
    __shared__ float mu_s, rs_s;
    int wid = tid>>6, lid = tid&63;
    if (lid==0){ ws_[wid]=s; wq_[wid]=sq; }
    __syncthreads();
    if (tid==0){
        float S=0,Q=0;
        for(int i=0;i<4;i++){S+=ws_[i];Q+=wq_[i];}
        float mu = S*(1.f/512.f);
        float var = Q*(1.f/512.f)-mu*mu;
        mu_s=mu; rs_s=rsqrtf(var+1e-5f);
    }
    __syncthreads();
    float mu=mu_s, rs=rs_s;
    float2 gv = reinterpret_cast<const float2*>(g)[tid];
    float2 bv = reinterpret_cast<const float2*>(be)[tid];
    v2h o; o[0] = (_Float16)((v.x-mu)*rs*gv.x + bv.x);
           o[1] = (_Float16)((v.y-mu)*rs*gv.y + bv.y);
    reinterpret_cast<v2h*>(xn + (size_t)row*512)[tid] = o;
}

// ---------------- weight transpose: W (512,512) fp32 -> WT (N,K) fp16 --------
__global__ __launch_bounds__(256) void k_wT(const float* __restrict__ W,
                                            _Float16* __restrict__ WT){
    __shared__ float tile[64][65];
    int bx = blockIdx.x*64, by = blockIdx.y*64;   // bx: n-base, by: k-base
    int tid = threadIdx.x, c = tid&63;
    for (int r = tid>>6; r<64; r+=4) tile[r][c] = W[(size_t)(by+r)*512 + bx + c];
    __syncthreads();
    for (int n = tid>>6; n<64; n+=4) WT[(size_t)(bx+n)*512 + by + c] = (_Float16)tile[c][n];
}

// ---------------- wcqT = (Wc @ Wq)^T fp16 [512][256] ----------------
__global__ __launch_bounds__(512) void k_wcq(const float* __restrict__ Wc,
                                             const float* __restrict__ Wq,
                                             _Float16* __restrict__ wcqT){
    __shared__ float wc[8][512];
    int i0 = blockIdx.x*8; int tid = threadIdx.x;
    for (int r=0;r<8;r++) wc[r][tid] = Wc[(size_t)(i0+r)*512 + tid];
    __syncthreads();
    float acc[8] = {0,0,0,0,0,0,0,0};
    for (int m=0;m<512;m++){
        float wq = Wq[(size_t)m*512+tid];
        #pragma unroll
        for (int r=0;r<8;r++) acc[r] += wc[r][m]*wq;
    }
    // wcqT[n][k], n = tid, k = i0+r  (8 contiguous halfs per thread)
    for (int r=0;r<8;r++) wcqT[(size_t)tid*256 + i0 + r] = (_Float16)acc[r];
}

// ---------------- bcq = bc @ Wq + bq ----------------
__global__ __launch_bounds__(512) void k_bcq(const float* __restrict__ bc,
                                             const float* __restrict__ Wq,
                                             const float* __restrict__ bq,
                                             float* __restrict__ bcq){
    int j = threadIdx.x;
    float a = bq[j];
    for (int m=0;m<512;m++) a += bc[m]*Wq[(size_t)m*512+j];
    bcq[j] = a;
}

// ---------------- GEMM v2: C(M,N) = (A(M,K) @ WT(N,K)^T + bias)*scale --------
// BM=64, BN=64, BK=64, 256 thr (4 waves). WT is fp16 [N][K]. Swizzled LDS.
template<typename AT, typename CT, bool QB>
__global__ __launch_bounds__(256) void k_gemm(const AT* __restrict__ A,
                                              const _Float16* __restrict__ WT,
                                              const float* __restrict__ bias,
                                              CT* __restrict__ C,
                                              int M, int N, int K,
                                              float scale,
                                              _Float16* __restrict__ qbT){
    __shared__ _Float16 Al[64*64];
    __shared__ _Float16 Wl[64*64];
    int tid = threadIdx.x; int l = tid & 63; int w = tid >> 6;
    int l15 = l & 15, lq = l >> 4;
    int m0 = blockIdx.y*64, n0 = blockIdx.x*64;
    v4f acc[4] = {};
    float bv[4];
    #pragma unroll
    for (int nt=0;nt<4;nt++) bv[nt] = bias[n0 + nt*16 + l15];
    int srow = tid>>2, sseg = (tid&3)*16;
    for (int k0=0;k0<K;k0+=64){
        // stage A tile (64 rows x 64 k) as fp16, vectorized
        if constexpr (sizeof(AT)==4){
            const float* src = (const float*)A + (size_t)(m0+srow)*K + k0 + sseg;
            float4 f0 = *(const float4*)src;
            float4 f1 = *(const float4*)(src+4);
            float4 f2 = *(const float4*)(src+8);
            float4 f3 = *(const float4*)(src+12);
            st8(&Al[swz(srow, sseg)],   cvt8(f0,f1));
            st8(&Al[swz(srow, sseg+8)], cvt8(f2,f3));
        } else {
            const _Float16* src = (const _Float16*)A + (size_t)(m0+srow)*K + k0 + sseg;
            v8h h0 = *(const v8h*)src;
            v8h h1 = *(const v8h*)(src+8);
            st8(&Al[swz(srow, sseg)],   h0);
            st8(&Al[swz(srow, sseg+8)], h1);
        }
        // stage W tile (64 n x 64 k), already [n][k] fp16
        {
            const _Float16* src = WT + (size_t)(n0+srow)*K + k0 + sseg;
            v8h h0 = *(const v8h*)src;
            v8h h1 = *(const v8h*)(src+8);
            st8(&Wl[swz(srow, sseg)],   h0);
            st8(&Wl[swz(srow, sseg+8)], h1);
        }
        __syncthreads();
        #pragma unroll
        for (int kk=0; kk<2; ++kk){
            v8h a = *(const v8h*)&Al[swz(w*16 + l15, kk*32 + lq*8)];
            #pragma unroll
            for (int nt=0;nt<4;nt++){
                v8h b = *(const v8h*)&Wl[swz(nt*16 + l15, kk*32 + lq*8)];
                acc[nt] = MFMA32(a, b, acc[nt]);
            }
        }
        __syncthreads();
    }
    #pragma unroll
    for (int nt=0;nt<4;nt++){
        #pragma unroll
        for (int i=0;i<4;i++){
            int row = m0 + w*16 + lq*4 + i;
            int col = n0 + nt*16 + l15;
            float vfull = (acc[nt][i] + bv[nt])*scale;
            C[(size_t)row*N + col] = (CT)vfull;
            if constexpr (QB){
                int bI = row>>10, t = row&1023;
                qbT[((size_t)t<<12) + (bI<<9) + col] = (_Float16)vfull;
            }
        }
    }
}

// ---------------- bias v3: Sb[t][bh][s] = qb[t,bh,:]·posk[t,s,:], mask folded
// 32x32x16 MFMA: A = qb (rows = bh), B = posk (cols = s). Full-line stores.
// grid 2048 (t = blk>>1, s-half = blk&1), 256 thr; wave w owns 128 s.
__global__ __launch_bounds__(256) void k_bias(const _Float16* __restrict__ qb,
                                              const float* __restrict__ posk,
                                              const int* __restrict__ mask,
                                              _Float16* __restrict__ Sb){
    int t = blockIdx.x >> 1, sh = blockIdx.x & 1;
    int tid = threadIdx.x, l = tid&63, w = tid>>6;
    int l31 = l&31, hi = l>>5;
    // A-frags: 2 bh-groups (bh0 = g*32), 4 k-chunks of 16
    v8h aa[2][4];
    const _Float16* qbt = qb + ((size_t)t<<12);
    #pragma unroll
    for (int g=0; g<2; ++g)
        #pragma unroll
        for (int k0=0;k0<4;++k0)
            aa[g][k0] = *(const v8h*)(qbt + (g*32 + l31)*64 + k0*16 + hi*8);
    const float* pkt = posk + ((size_t)t<<16);
    int sbase = sh*512 + w*128;
    #pragma unroll 2
    for (int sg=0; sg<4; ++sg){
        int s0 = sbase + sg*32;
        const float* prow = pkt + (size_t)(s0 + l31)*64 + hi*8;
        v8h bfr[4];
        #pragma unroll
        for (int k0=0;k0<4;++k0){
            float4 f0 = *(const float4*)(prow + k0*16);
            float4 f1 = *(const float4*)(prow + k0*16 + 4);
            bfr[k0] = cvt8(f0,f1);
        }
        #pragma unroll
        for (int g=0; g<2; ++g){
            v16f acc = {};
            #pragma unroll
            for (int k0=0;k0<4;++k0) acc = MFMA3216(aa[g][k0], bfr[k0], acc);
            // C layout: col = s = s0 + l31, row-in-group = (r&3) + 4*hi + 8*(r>>2)
            int mv[4];
            #pragma unroll
            for (int q=0;q<4;++q){
                int b = g*4 + q;      // bh>>3 = g*4 + (r>>2)
                mv[q] = mask[(((size_t)(b*Tt + t))<<10) + s0 + l31];
            }
            #pragma unroll
            for (int r=0;r<16;++r){
                int bh = g*32 + (r&3) + 4*hi + 8*(r>>2);
                _Float16 val = mv[r>>2] ? (_Float16)acc[r] : (_Float16)(-30000.f);
                Sb[(((size_t)(t*64 + bh))<<10) + s0 + l31] = val;   // stride 1024 (bug fix)
            }
        }
    }
}

// ---------------- flash: content QK + bias + online softmax + PV -------------
// grid (64 bh, 16 t-tiles of 64), 256 thr (4 waves, each owns 16 t-rows)
__global__ __launch_bounds__(256) void k_flash(const _Float16* __restrict__ qs,
                                               const _Float16* __restrict__ kbuf,
                                               const _Float16* __restrict__ vbuf,
                                               const _Float16* __restrict__ Sb,
                                               _Float16* __restrict__ ao){
    __shared__ _Float16 Kl[64*64];   // [s][d] swizzled
    __shared__ _Float16 Vt[64*64];   // [d][s] swizzled
    __shared__ _Float16 Bl[64*64];   // bias chunk then P, [t][s] swizzled
    int bh = blockIdx.x; int b = bh>>3, h = bh&7;
    int t0 = blockIdx.y*64;
    int tid = threadIdx.x, l = tid&63, w = tid>>6, l15 = l&15, lq = l>>4;

    // resident Q A-frags (scaled fp16), rows t0 + w*16 + l15
    v8h qa[2];
    #pragma unroll
    for (int u=0;u<2;++u)
        qa[u] = *(const v8h*)(qs + ((size_t)(b*Tt + t0 + w*16 + l15))*NFf + h*DKk + u*32 + lq*8);

    v4f O[4] = {};
    float mrow[4], lrow[4];
    #pragma unroll
    for (int i=0;i<4;i++){ mrow[i] = -1e30f; lrow[i] = 0.f; }

    for (int sc=0; sc<16; ++sc){
        int s0 = sc*64;
        {   // stage K chunk [64 s][64 d]
            int r = tid>>2, seg = tid&3;
            const v8h* src = (const v8h*)(kbuf + ((size_t)(b*Tt + s0 + r))*NFf + h*DKk + seg*16);
            v8h k0 = src[0], k1 = src[1];
            *(v8h*)&Kl[swz(r, seg*16)]   = k0;
            *(v8h*)&Kl[swz(r, seg*16+8)] = k1;
        }
        {   // stage V transposed -> Vt[d][s]
            int s = tid&63;
            #pragma unroll
            for (int half=0; half<2; ++half){
                int d0 = (tid>>6)*8 + half*32;
                v8h vv = *(const v8h*)(vbuf + ((size_t)(b*Tt + s0 + s))*NFf + h*DKk + d0);
                #pragma unroll
                for (int j=0;j<8;j++) Vt[swz(d0+j, s)] = vv[j];
            }
        }
        {   // stage bias chunk [64 t][64 s], Sb layout [t][bh][s] stride 1024
            int r = tid>>2, hf = tid&3;
            const v8h* src = (const v8h*)(Sb + (((size_t)(t0+r))<<16) + ((size_t)bh<<10) + s0 + hf*16);
            v8h b0 = src[0], b1 = src[1];
            *(v8h*)&Bl[swz(r, hf*16)]   = b0;
            *(v8h*)&Bl[swz(r, hf*16+8)] = b1;
        }
        __syncthreads();

        v4f sv[4];
        #pragma unroll
        for (int nt=0; nt<4; ++nt){
            v8h kb0 = *(v8h*)&Kl[swz(nt*16+l15, lq*8)];
            v8h kb1 = *(v8h*)&Kl[swz(nt*16+l15, 32+lq*8)];
            v4f a = {};
            a = MFMA32(qa[0], kb0, a);
            a = MFMA32(qa[1], kb1, a);
            int rb = w*16;
            #pragma unroll
            for (int i=0;i<4;i++)
                a[i] += (float)Bl[swz(rb + lq*4 + i, nt*16 + l15)];
            sv[nt] = a;
        }
        #pragma unroll
        for (int i=0;i<4;i++){
            float mx = fmaxf(fmaxf(sv[0][i],sv[1][i]),fmaxf(sv[2][i],sv[3][i]));
            mx = fmaxf(mx, __shfl_xor(mx,1));
            mx = fmaxf(mx, __shfl_xor(mx,2));
            mx = fmaxf(mx, __shfl_xor(mx,4));
            mx = fmaxf(mx, __shfl_xor(mx,8));
            float mo = mrow[i];
            float mn = fmaxf(mo, mx);
            float rsc = exp2f(mo - mn);
            mrow[i] = mn;
            lrow[i] *= rsc;
            #pragma unroll
            for (int nt=0; nt<4; ++nt) O[nt][i] *= rsc;
            float ps = 0.f;
            #pragma unroll
            for (int nt=0; nt<4; ++nt){
                float pv = exp2f(sv[nt][i] - mn);
                sv[nt][i] = pv;
                ps += pv;
            }
            ps += __shfl_xor(ps,1);
            ps += __shfl_xor(ps,2);
            ps += __shfl_xor(ps,4);
            ps += __shfl_xor(ps,8);
            lrow[i] += ps;
        }
        // write P (fp16) into Bl over this wave's rows
        #pragma unroll
        for (int nt=0;nt<4;++nt){
            #pragma unroll
            for (int i=0;i<4;i++)
                Bl[swz(w*16+lq*4+i, nt*16+l15)] = (_Float16)sv[nt][i];
        }
        // PV: A = P rows (own wave), B = Vt
        {
            v8h pa0 = *(v8h*)&Bl[swz(w*16+l15, lq*8)];
            v8h pa1 = *(v8h*)&Bl[swz(w*16+l15, 32+lq*8)];
            #pragma unroll
            for (int nt=0; nt<4; ++nt){
                v8h vb0 = *(v8h*)&Vt[swz(nt*16+l15, lq*8)];
                v8h vb1 = *(v8h*)&Vt[swz(nt*16+l15, 32+lq*8)];
                O[nt] = MFMA32(pa0, vb0, O[nt]);
                O[nt] = MFMA32(pa1, vb1, O[nt]);
            }
        }
        __syncthreads();
    }

    #pragma unroll
    for (int i=0;i<4;i++){
        float lr = lrow[i];
        float rl = (lr > 0.f) ? 1.f/lr : 0.f;
        int row = t0 + w*16 + lq*4 + i;
        #pragma unroll
        for (int nt=0; nt<4; ++nt)
            ao[((size_t)(b*Tt + row))*NFf + h*DKk + nt*16 + l15] = (_Float16)(O[nt][i]*rl);
    }
}

// ---------------- launch ----------------
extern "C" void kernel_launch(void* const* d_in, const int* in_sizes, int n_in,
                              void* d_out, int out_size, void* d_ws, size_t ws_size,
                              hipStream_t stream) {
    const float* x       = (const float*)d_in[0];
    const float* cond    = (const float*)d_in[1];
    const float* pos_k   = (const float*)d_in[2];
    const int*   mask    = (const int*)  d_in[3];
    const float* ln_g    = (const float*)d_in[4];
    const float* ln_b    = (const float*)d_in[5];
    const float* Wq      = (const float*)d_in[6];
    const float* bq      = (const float*)d_in[7];
    const float* Wk      = (const float*)d_in[8];
    const float* bk      = (const float*)d_in[9];
    const float* Wv      = (const float*)d_in[10];
    const float* bv      = (const float*)d_in[11];
    const float* Wo      = (const float*)d_in[12];
    const float* bo      = (const float*)d_in[13];
    const float* Wc      = (const float*)d_in[14];
    const float* bc      = (const float*)d_in[15];
    float* out = (float*)d_out;

    char* base = (char*)d_ws;
    const size_t OFF_S    = 0;                       // 134217728 B fp16 Sb
    const size_t OFF_XN   = 134217728;
    const size_t OFF_Q    = OFF_XN  + 8388608;
    const size_t OFF_QB   = OFF_Q   + 8388608;
    const size_t OFF_K    = OFF_QB  + 8388608;
    const size_t OFF_V    = OFF_K   + 8388608;
    const size_t OFF_AO   = OFF_V   + 8388608;
    const size_t OFF_WKT  = OFF_AO  + 8388608;       // 524288
    const size_t OFF_WVT  = OFF_WKT + 524288;
    const size_t OFF_WOT  = OFF_WVT + 524288;
    const size_t OFF_WCQT = OFF_WOT + 524288;        // 262144
    const size_t OFF_BCQ  = OFF_WCQT + 262144;

    _Float16* xn    = (_Float16*)(base + OFF_XN);
    _Float16* qbuf  = (_Float16*)(base + OFF_Q);
    _Float16* qb    = (_Float16*)(base + OFF_QB);
    _Float16* kb    = (_Float16*)(base + OFF_K);
    _Float16* vb    = (_Float16*)(base + OFF_V);
    _Float16* ao    = (_Float16*)(base + OFF_AO);
    _Float16* Sb    = (_Float16*)(base + OFF_S);
    _Float16* WkT   = (_Float16*)(base + OFF_WKT);
    _Float16* WvT   = (_Float16*)(base + OFF_WVT);
    _Float16* WoT   = (_Float16*)(base + OFF_WOT);
    _Float16* wcqT  = (_Float16*)(base + OFF_WCQT);
    float*    bcq   = (float*)(base + OFF_BCQ);

    k_ln<<<dim3(Bb*Tt), dim3(256), 0, stream>>>(x, ln_g, ln_b, xn);
    k_wT<<<dim3(8,8), dim3(256), 0, stream>>>(Wk, WkT);
    k_wT<<<dim3(8,8), dim3(256), 0, stream>>>(Wv, WvT);
    k_wT<<<dim3(8,8), dim3(256), 0, stream>>>(Wo, WoT);
    k_wcq<<<dim3(32), dim3(512), 0, stream>>>(Wc, Wq, wcqT);
    k_bcq<<<dim3(1), dim3(512), 0, stream>>>(bc, Wq, bq, bcq);

    // q projection: writes scaled qbuf AND scaled transposed qb
    k_gemm<float,_Float16,true><<<dim3(8,128), dim3(256), 0, stream>>>(cond, wcqT, bcq, qbuf, Bb*Tt, 512, 256, SCQ, qb);
    k_gemm<_Float16,_Float16,false><<<dim3(8,128), dim3(256), 0, stream>>>(xn, WkT, bk, kb, Bb*Tt, 512, 512, 1.f, nullptr);
    k_gemm<_Float16,_Float16,false><<<dim3(8,128), dim3(256), 0, stream>>>(xn, WvT, bv, vb, Bb*Tt, 512, 512, 1.f, nullptr);

    k_bias<<<dim3(2048), dim3(256), 0, stream>>>(qb, pos_k, mask, Sb);
    k_flash<<<dim3(64,16), dim3(256), 0, stream>>>(qbuf, kb, vb, Sb, ao);

    k_gemm<_Float16,float,false><<<dim3(8,128), dim3(256), 0, stream>>>(ao, WoT, bo, out, Bb*Tt, 512, 512, 1.f, nullptr);
}

// Round 8
// 377.656 us; speedup vs baseline: 1.0855x; 1.0855x over previous
//
#include <hip/hip_runtime.h>

// ---------------- problem constants ----------------
#define Bb 8
#define Tt 1024
#define Hh 8
#define DKk 64
#define NFf 512
#define DCc 256

typedef _Float16 v2h __attribute__((ext_vector_type(2)));
typedef _Float16 v4h __attribute__((ext_vector_type(4)));
typedef _Float16 v8h __attribute__((ext_vector_type(8)));
typedef float    v4f __attribute__((ext_vector_type(4)));
typedef float    v16f __attribute__((ext_vector_type(16)));

#define MFMA32(a,b,c) __builtin_amdgcn_mfma_f32_16x16x32_f16((a),(b),(c),0,0,0)
#define MFMA3216(a,b,c) __builtin_amdgcn_mfma_f32_32x32x16_f16((a),(b),(c),0,0,0)

// scale folded into q: 1/sqrt(64) * log2(e)  (scores live in log2 domain)
#define SCQ 0.1803368801111f

__device__ inline void st8(_Float16* dst, v8h x){
    *(v4h*)dst     = __builtin_shufflevector(x,x,0,1,2,3);
    *(v4h*)(dst+4) = __builtin_shufflevector(x,x,4,5,6,7);
}

__device__ inline v8h cvt8(float4 a, float4 b){
    v8h r;
    r[0]=(_Float16)a.x; r[1]=(_Float16)a.y; r[2]=(_Float16)a.z; r[3]=(_Float16)a.w;
    r[4]=(_Float16)b.x; r[5]=(_Float16)b.y; r[6]=(_Float16)b.z; r[7]=(_Float16)b.w;
    return r;
}

__device__ inline v8h cvt8v(v4f a, v4f b){
    v8h r;
    r[0]=(_Float16)a[0]; r[1]=(_Float16)a[1]; r[2]=(_Float16)a[2]; r[3]=(_Float16)a[3];
    r[4]=(_Float16)b[0]; r[5]=(_Float16)b[1]; r[6]=(_Float16)b[2]; r[7]=(_Float16)b[3];
    return r;
}

__device__ inline v4f ntl4(const float* p){
    return __builtin_nontemporal_load(reinterpret_cast<const v4f*>(p));
}

// XOR swizzle for [R][64] half LDS tiles; keeps 8-half granularity
__device__ inline int swz(int r, int c){ return (r*64 + c) ^ ((r&7)<<3); }

// ---------------- LayerNorm: x (8192,512) fp32 -> xn fp16 ----------------
__global__ __launch_bounds__(256) void k_ln(const float* __restrict__ x,
                                            const float* __restrict__ g,
                                            const float* __restrict__ be,
                                            _Float16* __restrict__ xn){
    int row = blockIdx.x; int tid = threadIdx.x;
    const float* xr = x + (size_t)row*512;
    float2 v = reinterpret_cast<const float2*>(xr)[tid];
    float s = v.x + v.y, sq = v.x*v.x + v.y*v.y;
    for (int off=32; off; off>>=1){ s += __shfl_down(s, off); sq += __shfl_down(sq, off); }
    __shared__ float ws_[4], wq_[4];
    __shared__ float mu_s, rs_s;
    int wid = tid>>6, lid = tid&63;
    if (lid==0){ ws_[wid]=s; wq_[wid]=sq; }
    __syncthreads();
    if (tid==0){
        float S=0,Q=0;
        for(int i=0;i<4;i++){S+=ws_[i];Q+=wq_[i];}
        float mu = S*(1.f/512.f);
        float var = Q*(1.f/512.f)-mu*mu;
        mu_s=mu; rs_s=rsqrtf(var+1e-5f);
    }
    __syncthreads();
    float mu=mu_s, rs=rs_s;
    float2 gv = reinterpret_cast<const float2*>(g)[tid];
    float2 bv = reinterpret_cast<const float2*>(be)[tid];
    v2h o; o[0] = (_Float16)((v.x-mu)*rs*gv.x + bv.x);
           o[1] = (_Float16)((v.y-mu)*rs*gv.y + bv.y);
    reinterpret_cast<v2h*>(xn + (size_t)row*512)[tid] = o;
}

// ---------------- weight transpose: W (512,512) fp32 -> WT (N,K) fp16 --------
__global__ __launch_bounds__(256) void k_wT(const float* __restrict__ W,
                                            _Float16* __restrict__ WT){
    __shared__ float tile[64][65];
    int bx = blockIdx.x*64, by = blockIdx.y*64;   // bx: n-base, by: k-base
    int tid = threadIdx.x, c = tid&63;
    for (int r = tid>>6; r<64; r+=4) tile[r][c] = W[(size_t)(by+r)*512 + bx + c];
    __syncthreads();
    for (int n = tid>>6; n<64; n+=4) WT[(size_t)(bx+n)*512 + by + c] = (_Float16)tile[c][n];
}

// ---------------- wcqT = (Wc @ Wq)^T fp16 [512][256] ----------------
__global__ __launch_bounds__(512) void k_wcq(const float* __restrict__ Wc,
                                             const float* __restrict__ Wq,
                                             _Float16* __restrict__ wcqT){
    __shared__ float wc[8][512];
    int i0 = blockIdx.x*8; int tid = threadIdx.x;
    for (int r=0;r<8;r++) wc[r][tid] = Wc[(size_t)(i0+r)*512 + tid];
    __syncthreads();
    float acc[8] = {0,0,0,0,0,0,0,0};
    for (int m=0;m<512;m++){
        float wq = Wq[(size_t)m*512+tid];
        #pragma unroll
        for (int r=0;r<8;r++) acc[r] += wc[r][m]*wq;
    }
    for (int r=0;r<8;r++) wcqT[(size_t)tid*256 + i0 + r] = (_Float16)acc[r];
}

// ---------------- bcq = bc @ Wq + bq ----------------
__global__ __launch_bounds__(512) void k_bcq(const float* __restrict__ bc,
                                             const float* __restrict__ Wq,
                                             const float* __restrict__ bq,
                                             float* __restrict__ bcq){
    int j = threadIdx.x;
    float a = bq[j];
    for (int m=0;m<512;m++) a += bc[m]*Wq[(size_t)m*512+j];
    bcq[j] = a;
}

// ---------------- GEMM v2: C(M,N) = (A(M,K) @ WT(N,K)^T + bias)*scale --------
template<typename AT, typename CT, bool QB>
__global__ __launch_bounds__(256) void k_gemm(const AT* __restrict__ A,
                                              const _Float16* __restrict__ WT,
                                              const float* __restrict__ bias,
                                              CT* __restrict__ C,
                                              int M, int N, int K,
                                              float scale,
                                              _Float16* __restrict__ qbT){
    __shared__ _Float16 Al[64*64];
    __shared__ _Float16 Wl[64*64];
    int tid = threadIdx.x; int l = tid & 63; int w = tid >> 6;
    int l15 = l & 15, lq = l >> 4;
    int m0 = blockIdx.y*64, n0 = blockIdx.x*64;
    v4f acc[4] = {};
    float bv[4];
    #pragma unroll
    for (int nt=0;nt<4;nt++) bv[nt] = bias[n0 + nt*16 + l15];
    int srow = tid>>2, sseg = (tid&3)*16;
    for (int k0=0;k0<K;k0+=64){
        if constexpr (sizeof(AT)==4){
            const float* src = (const float*)A + (size_t)(m0+srow)*K + k0 + sseg;
            float4 f0 = *(const float4*)src;
            float4 f1 = *(const float4*)(src+4);
            float4 f2 = *(const float4*)(src+8);
            float4 f3 = *(const float4*)(src+12);
            st8(&Al[swz(srow, sseg)],   cvt8(f0,f1));
            st8(&Al[swz(srow, sseg+8)], cvt8(f2,f3));
        } else {
            const _Float16* src = (const _Float16*)A + (size_t)(m0+srow)*K + k0 + sseg;
            v8h h0 = *(const v8h*)src;
            v8h h1 = *(const v8h*)(src+8);
            st8(&Al[swz(srow, sseg)],   h0);
            st8(&Al[swz(srow, sseg+8)], h1);
        }
        {
            const _Float16* src = WT + (size_t)(n0+srow)*K + k0 + sseg;
            v8h h0 = *(const v8h*)src;
            v8h h1 = *(const v8h*)(src+8);
            st8(&Wl[swz(srow, sseg)],   h0);
            st8(&Wl[swz(srow, sseg+8)], h1);
        }
        __syncthreads();
        #pragma unroll
        for (int kk=0; kk<2; ++kk){
            v8h a = *(const v8h*)&Al[swz(w*16 + l15, kk*32 + lq*8)];
            #pragma unroll
            for (int nt=0;nt<4;nt++){
                v8h b = *(const v8h*)&Wl[swz(nt*16 + l15, kk*32 + lq*8)];
                acc[nt] = MFMA32(a, b, acc[nt]);
            }
        }
        __syncthreads();
    }
    #pragma unroll
    for (int nt=0;nt<4;nt++){
        #pragma unroll
        for (int i=0;i<4;i++){
            int row = m0 + w*16 + lq*4 + i;
            int col = n0 + nt*16 + l15;
            float vfull = (acc[nt][i] + bv[nt])*scale;
            C[(size_t)row*N + col] = (CT)vfull;
            if constexpr (QB){
                int bI = row>>10, t = row&1023;
                qbT[((size_t)t<<12) + (bI<<9) + col] = (_Float16)vfull;
            }
        }
    }
}

// ---------------- fused K+V projection: one A-stage, two MFMA streams --------
__global__ __launch_bounds__(256) void k_gemmkv(const _Float16* __restrict__ A,
                                                const _Float16* __restrict__ WTk,
                                                const _Float16* __restrict__ WTv,
                                                const float* __restrict__ bk,
                                                const float* __restrict__ bv,
                                                _Float16* __restrict__ Ck,
                                                _Float16* __restrict__ Cv){
    __shared__ _Float16 Al[64*64];
    __shared__ _Float16 Wkl[64*64];
    __shared__ _Float16 Wvl[64*64];
    int tid = threadIdx.x; int l = tid & 63; int w = tid >> 6;
    int l15 = l & 15, lq = l >> 4;
    int m0 = blockIdx.y*64, n0 = blockIdx.x*64;
    v4f ak[4] = {}, av[4] = {};
    float bkr[4], bvr[4];
    #pragma unroll
    for (int nt=0;nt<4;nt++){ bkr[nt] = bk[n0 + nt*16 + l15]; bvr[nt] = bv[n0 + nt*16 + l15]; }
    int srow = tid>>2, sseg = (tid&3)*16;
    for (int k0=0;k0<512;k0+=64){
        {
            const _Float16* src = A + (size_t)(m0+srow)*512 + k0 + sseg;
            v8h h0 = *(const v8h*)src;
            v8h h1 = *(const v8h*)(src+8);
            st8(&Al[swz(srow, sseg)],   h0);
            st8(&Al[swz(srow, sseg+8)], h1);
        }
        {
            const _Float16* src = WTk + (size_t)(n0+srow)*512 + k0 + sseg;
            v8h h0 = *(const v8h*)src;
            v8h h1 = *(const v8h*)(src+8);
            st8(&Wkl[swz(srow, sseg)],   h0);
            st8(&Wkl[swz(srow, sseg+8)], h1);
        }
        {
            const _Float16* src = WTv + (size_t)(n0+srow)*512 + k0 + sseg;
            v8h h0 = *(const v8h*)src;
            v8h h1 = *(const v8h*)(src+8);
            st8(&Wvl[swz(srow, sseg)],   h0);
            st8(&Wvl[swz(srow, sseg+8)], h1);
        }
        __syncthreads();
        #pragma unroll
        for (int kk=0; kk<2; ++kk){
            v8h a = *(const v8h*)&Al[swz(w*16 + l15, kk*32 + lq*8)];
            #pragma unroll
            for (int nt=0;nt<4;nt++){
                v8h wk = *(const v8h*)&Wkl[swz(nt*16 + l15, kk*32 + lq*8)];
                v8h wv = *(const v8h*)&Wvl[swz(nt*16 + l15, kk*32 + lq*8)];
                ak[nt] = MFMA32(a, wk, ak[nt]);
                av[nt] = MFMA32(a, wv, av[nt]);
            }
        }
        __syncthreads();
    }
    #pragma unroll
    for (int nt=0;nt<4;nt++){
        #pragma unroll
        for (int i=0;i<4;i++){
            int row = m0 + w*16 + lq*4 + i;
            int col = n0 + nt*16 + l15;
            Ck[(size_t)row*512 + col] = (_Float16)(ak[nt][i] + bkr[nt]);
            Cv[(size_t)row*512 + col] = (_Float16)(av[nt][i] + bvr[nt]);
        }
    }
}

// ---------------- bias v3: Sb[t][bh][s] = qb[t,bh,:]·posk[t,s,:], mask folded
// 32x32x16 MFMA: A = qb (rows = bh), B = posk (cols = s). Nontemporal streams.
__global__ __launch_bounds__(256) void k_bias(const _Float16* __restrict__ qb,
                                              const float* __restrict__ posk,
                                              const int* __restrict__ mask,
                                              _Float16* __restrict__ Sb){
    int t = blockIdx.x >> 1, sh = blockIdx.x & 1;
    int tid = threadIdx.x, l = tid&63, w = tid>>6;
    int l31 = l&31, hi = l>>5;
    v8h aa[2][4];
    const _Float16* qbt = qb + ((size_t)t<<12);
    #pragma unroll
    for (int g=0; g<2; ++g)
        #pragma unroll
        for (int k0=0;k0<4;++k0)
            aa[g][k0] = *(const v8h*)(qbt + (g*32 + l31)*64 + k0*16 + hi*8);
    const float* pkt = posk + ((size_t)t<<16);
    int sbase = sh*512 + w*128;
    #pragma unroll 2
    for (int sg=0; sg<4; ++sg){
        int s0 = sbase + sg*32;
        const float* prow = pkt + (size_t)(s0 + l31)*64 + hi*8;
        v8h bfr[4];
        #pragma unroll
        for (int k0=0;k0<4;++k0){
            v4f f0 = ntl4(prow + k0*16);
            v4f f1 = ntl4(prow + k0*16 + 4);
            bfr[k0] = cvt8v(f0,f1);
        }
        #pragma unroll
        for (int g=0; g<2; ++g){
            v16f acc = {};
            #pragma unroll
            for (int k0=0;k0<4;++k0) acc = MFMA3216(aa[g][k0], bfr[k0], acc);
            int mv[4];
            #pragma unroll
            for (int q=0;q<4;++q){
                int b = g*4 + q;      // bh>>3 = g*4 + (r>>2)
                mv[q] = mask[(((size_t)(b*Tt + t))<<10) + s0 + l31];
            }
            #pragma unroll
            for (int r=0;r<16;++r){
                int bh = g*32 + (r&3) + 4*hi + 8*(r>>2);
                _Float16 val = mv[r>>2] ? (_Float16)acc[r] : (_Float16)(-30000.f);
                __builtin_nontemporal_store(val, &Sb[(((size_t)(t*64 + bh))<<10) + s0 + l31]);
            }
        }
    }
}

// ---------------- flash: content QK + bias + online softmax + PV -------------
// grid (64 bh, 8 t-tiles of 128), 512 thr (8 waves, each owns 16 t-rows)
__global__ __launch_bounds__(512) void k_flash(const _Float16* __restrict__ qs,
                                               const _Float16* __restrict__ kbuf,
                                               const _Float16* __restrict__ vbuf,
                                               const _Float16* __restrict__ Sb,
                                               _Float16* __restrict__ ao){
    __shared__ _Float16 Kl[64*64];    // [s][d] swizzled
    __shared__ _Float16 Vt[64*64];    // [d][s] swizzled
    __shared__ _Float16 Bl[128*64];   // bias chunk then P, [t][s] swizzled
    int bh = blockIdx.x; int b = bh>>3, h = bh&7;
    int t0 = blockIdx.y*128;
    int tid = threadIdx.x, l = tid&63, w = tid>>6, l15 = l&15, lq = l>>4;

    // resident Q A-frags (scaled fp16), rows t0 + w*16 + l15
    v8h qa[2];
    #pragma unroll
    for (int u=0;u<2;++u)
        qa[u] = *(const v8h*)(qs + ((size_t)(b*Tt + t0 + w*16 + l15))*NFf + h*DKk + u*32 + lq*8);

    v4f O[4] = {};
    float mrow[4], lrow[4];
    #pragma unroll
    for (int i=0;i<4;i++){ mrow[i] = -1e30f; lrow[i] = 0.f; }

    for (int sc=0; sc<16; ++sc){
        int s0 = sc*64;
        {   // stage K chunk [64 s][64 d]: 512 thr, 1 v8h each
            int r = tid>>3, seg = (tid&7)*8;
            v8h k0 = *(const v8h*)(kbuf + ((size_t)(b*Tt + s0 + r))*NFf + h*DKk + seg);
            st8(&Kl[swz(r, seg)], k0);
        }
        {   // stage V transposed -> Vt[d][s]
            int s = tid&63;
            int d0 = (tid>>6)*8;
            v8h vv = *(const v8h*)(vbuf + ((size_t)(b*Tt + s0 + s))*NFf + h*DKk + d0);
            #pragma unroll
            for (int j=0;j<8;j++) Vt[swz(d0+j, s)] = vv[j];
        }
        {   // stage bias chunk [128 t][64 s], Sb layout [t][bh][s]
            int r = tid>>2, hf = (tid&3)*16;
            const v8h* src = (const v8h*)(Sb + (((size_t)((t0+r)*64 + bh))<<10) + s0 + hf);
            v8h b0 = __builtin_nontemporal_load(src);
            v8h b1 = __builtin_nontemporal_load(src+1);
            st8(&Bl[swz(r, hf)],   b0);
            st8(&Bl[swz(r, hf+8)], b1);
        }
        __syncthreads();

        v4f sv[4];
        #pragma unroll
        for (int nt=0; nt<4; ++nt){
            v8h kb0 = *(v8h*)&Kl[swz(nt*16+l15, lq*8)];
            v8h kb1 = *(v8h*)&Kl[swz(nt*16+l15, 32+lq*8)];
            v4f a = {};
            a = MFMA32(qa[0], kb0, a);
            a = MFMA32(qa[1], kb1, a);
            int rb = w*16;
            #pragma unroll
            for (int i=0;i<4;i++)
                a[i] += (float)Bl[swz(rb + lq*4 + i, nt*16 + l15)];
            sv[nt] = a;
        }
        // online softmax with defer-max (exact: skipping when no growth is bit-exact)
        float mn[4]; float grow = 0.f;
        #pragma unroll
        for (int i=0;i<4;i++){
            float mx = fmaxf(fmaxf(sv[0][i],sv[1][i]),fmaxf(sv[2][i],sv[3][i]));
            mx = fmaxf(mx, __shfl_xor(mx,1));
            mx = fmaxf(mx, __shfl_xor(mx,2));
            mx = fmaxf(mx, __shfl_xor(mx,4));
            mx = fmaxf(mx, __shfl_xor(mx,8));
            mn[i] = fmaxf(mrow[i], mx);
            grow = fmaxf(grow, mn[i] - mrow[i]);
        }
        if (__any(grow > 0.f)){
            #pragma unroll
            for (int i=0;i<4;i++){
                float rsc = exp2f(mrow[i] - mn[i]);
                mrow[i] = mn[i];
                lrow[i] *= rsc;
                #pragma unroll
                for (int nt=0; nt<4; ++nt) O[nt][i] *= rsc;
            }
        }
        #pragma unroll
        for (int i=0;i<4;i++){
            float ps = 0.f;
            #pragma unroll
            for (int nt=0; nt<4; ++nt){
                float pv = exp2f(sv[nt][i] - mrow[i]);
                sv[nt][i] = pv;
                ps += pv;
            }
            ps += __shfl_xor(ps,1);
            ps += __shfl_xor(ps,2);
            ps += __shfl_xor(ps,4);
            ps += __shfl_xor(ps,8);
            lrow[i] += ps;
        }
        // write P (fp16) into Bl over this wave's rows
        #pragma unroll
        for (int nt=0;nt<4;++nt){
            #pragma unroll
            for (int i=0;i<4;i++)
                Bl[swz(w*16+lq*4+i, nt*16+l15)] = (_Float16)sv[nt][i];
        }
        // PV: A = P rows (own wave), B = Vt
        {
            v8h pa0 = *(v8h*)&Bl[swz(w*16+l15, lq*8)];
            v8h pa1 = *(v8h*)&Bl[swz(w*16+l15, 32+lq*8)];
            #pragma unroll
            for (int nt=0; nt<4; ++nt){
                v8h vb0 = *(v8h*)&Vt[swz(nt*16+l15, lq*8)];
                v8h vb1 = *(v8h*)&Vt[swz(nt*16+l15, 32+lq*8)];
                O[nt] = MFMA32(pa0, vb0, O[nt]);
                O[nt] = MFMA32(pa1, vb1, O[nt]);
            }
        }
        __syncthreads();
    }

    #pragma unroll
    for (int i=0;i<4;i++){
        float lr = lrow[i];
        float rl = (lr > 0.f) ? 1.f/lr : 0.f;
        int row = t0 + w*16 + lq*4 + i;
        #pragma unroll
        for (int nt=0; nt<4; ++nt)
            ao[((size_t)(b*Tt + row))*NFf + h*DKk + nt*16 + l15] = (_Float16)(O[nt][i]*rl);
    }
}

// ---------------- launch ----------------
extern "C" void kernel_launch(void* const* d_in, const int* in_sizes, int n_in,
                              void* d_out, int out_size, void* d_ws, size_t ws_size,
                              hipStream_t stream) {
    const float* x       = (const float*)d_in[0];
    const float* cond    = (const float*)d_in[1];
    const float* pos_k   = (const float*)d_in[2];
    const int*   mask    = (const int*)  d_in[3];
    const float* ln_g    = (const float*)d_in[4];
    const float* ln_b    = (const float*)d_in[5];
    const float* Wq      = (const float*)d_in[6];
    const float* bq      = (const float*)d_in[7];
    const float* Wk      = (const float*)d_in[8];
    const float* bk      = (const float*)d_in[9];
    const float* Wv      = (const float*)d_in[10];
    const float* bv      = (const float*)d_in[11];
    const float* Wo      = (const float*)d_in[12];
    const float* bo      = (const float*)d_in[13];
    const float* Wc      = (const float*)d_in[14];
    const float* bc      = (const float*)d_in[15];
    float* out = (float*)d_out;

    char* base = (char*)d_ws;
    const size_t OFF_S    = 0;                       // 134217728 B fp16 Sb
    const size_t OFF_XN   = 134217728;
    const size_t OFF_Q    = OFF_XN  + 8388608;
    const size_t OFF_QB   = OFF_Q   + 8388608;
    const size_t OFF_K    = OFF_QB  + 8388608;
    const size_t OFF_V    = OFF_K   + 8388608;
    const size_t OFF_AO   = OFF_V   + 8388608;
    const size_t OFF_WKT  = OFF_AO  + 8388608;       // 524288
    const size_t OFF_WVT  = OFF_WKT + 524288;
    const size_t OFF_WOT  = OFF_WVT + 524288;
    const size_t OFF_WCQT = OFF_WOT + 524288;        // 262144
    const size_t OFF_BCQ  = OFF_WCQT + 262144;

    _Float16* xn    = (_Float16*)(base + OFF_XN);
    _Float16* qbuf  = (_Float16*)(base + OFF_Q);
    _Float16* qb    = (_Float16*)(base + OFF_QB);
    _Float16* kb    = (_Float16*)(base + OFF_K);
    _Float16* vb    = (_Float16*)(base + OFF_V);
    _Float16* ao    = (_Float16*)(base + OFF_AO);
    _Float16* Sb    = (_Float16*)(base + OFF_S);
    _Float16* WkT   = (_Float16*)(base + OFF_WKT);
    _Float16* WvT   = (_Float16*)(base + OFF_WVT);
    _Float16* WoT   = (_Float16*)(base + OFF_WOT);
    _Float16* wcqT  = (_Float16*)(base + OFF_WCQT);
    float*    bcq   = (float*)(base + OFF_BCQ);

    k_ln<<<dim3(Bb*Tt), dim3(256), 0, stream>>>(x, ln_g, ln_b, xn);
    k_wT<<<dim3(8,8), dim3(256), 0, stream>>>(Wk, WkT);
    k_wT<<<dim3(8,8), dim3(256), 0, stream>>>(Wv, WvT);
    k_wT<<<dim3(8,8), dim3(256), 0, stream>>>(Wo, WoT);
    k_wcq<<<dim3(32), dim3(512), 0, stream>>>(Wc, Wq, wcqT);
    k_bcq<<<dim3(1), dim3(512), 0, stream>>>(bc, Wq, bq, bcq);

    // q projection: writes scaled qbuf AND scaled transposed qb
    k_gemm<float,_Float16,true><<<dim3(8,128), dim3(256), 0, stream>>>(cond, wcqT, bcq, qbuf, Bb*Tt, 512, 256, SCQ, qb);
    // fused K+V projection
    k_gemmkv<<<dim3(8,128), dim3(256), 0, stream>>>(xn, WkT, WvT, bk, bv, kb, vb);

    k_bias<<<dim3(2048), dim3(256), 0, stream>>>(qb, pos_k, mask, Sb);
    k_flash<<<dim3(64,8), dim3(512), 0, stream>>>(qbuf, kb, vb, Sb, ao);

    k_gemm<_Float16,float,false><<<dim3(8,128), dim3(256), 0, stream>>>(ao, WoT, bo, out, Bb*Tt, 512, 512, 1.f, nullptr);
}